// Round 6
// baseline (341.144 us; speedup 1.0000x reference)
//
#include <hip/hip_runtime.h>

// MeanAggregator: out[b,:] = mean over DISTINCT nbrs[b,:] of features[idx,:]
// features: [N=200000, D=256] f32 (204.8 MB); nbrs: [B=32768, S=10]; out: [B,256] f32
//
// ROUND 6 = MEASUREMENT PROBE (intentional, temporary):
// The gather kernel never appears in the rocprof top-5 (all slots taken by
// the harness's 122us/819MB poison fills), so its dur and FETCH_SIZE are
// invisible. Three structural probes (LLC warm r1, occupancy r4, persistent
// pipelining r5) all nulled within noise -> the remaining hypotheses differ
// only in the gather's own numbers. This round launches the IDENTICAL
// gather twice (idempotent: second pass rewrites the same values; absmax
// stays 0). Readout:
//   dur - 290  = standalone cost of one (LLC-warm) gather pass.
//   ~+120 -> DRAM-random-page-bound (~2.8 TB/s ceiling for 1KB random rows)
//   ~+65  -> gather already at stream floor; dur dominated by harness
//   much-less-than-first-pass -> LLC reuse IS exploitable -> attack next.
//
// Kernel body = round-4 structure (fastest so far, 287.2us): one wave per
// row, scalar-path indices, 10 back-to-back saddr gathers, SALU dedupe,
// nontemporal store.

#define AGG_S 10
#define AGG_D 256

typedef __attribute__((ext_vector_type(4))) float f32x4;

__global__ __launch_bounds__(256, 8) void MeanAggregator_58514634441194_kernel(
    const float* __restrict__ feat,
    const int* __restrict__ nbrs,
    float* __restrict__ out,
    int B)
{
    const int tid  = blockIdx.x * blockDim.x + threadIdx.x;
    const int lane = threadIdx.x & 63;
    const int wave = __builtin_amdgcn_readfirstlane(tid >> 6);
    if (wave >= B) return;

    const int* __restrict__ row = nbrs + (size_t)wave * AGG_S;
    int idx[AGG_S];
#pragma unroll
    for (int s = 0; s < AGG_S; ++s)
        idx[s] = __builtin_amdgcn_readfirstlane(row[s]);

    float w[AGG_S];
    float cnt = 0.0f;
#pragma unroll
    for (int s = 0; s < AGG_S; ++s) {
        bool dup = false;
#pragma unroll
        for (int j = 0; j < AGG_S; ++j) {
            if (j < s) dup |= (idx[j] == idx[s]);
        }
        w[s] = dup ? 0.0f : 1.0f;
        cnt += w[s];
    }

    float4 v[AGG_S];
#pragma unroll
    for (int s = 0; s < AGG_S; ++s) {
        const float4* __restrict__ p =
            (const float4*)(feat + (size_t)idx[s] * AGG_D);
        v[s] = p[lane];
    }

    float4 acc = make_float4(0.f, 0.f, 0.f, 0.f);
#pragma unroll
    for (int s = 0; s < AGG_S; ++s) {
        acc.x = fmaf(w[s], v[s].x, acc.x);
        acc.y = fmaf(w[s], v[s].y, acc.y);
        acc.z = fmaf(w[s], v[s].z, acc.z);
        acc.w = fmaf(w[s], v[s].w, acc.w);
    }

    const float inv = 1.0f / cnt;
    acc.x *= inv; acc.y *= inv; acc.z *= inv; acc.w *= inv;

    f32x4 accv;
    accv.x = acc.x; accv.y = acc.y; accv.z = acc.z; accv.w = acc.w;
    f32x4* __restrict__ dst = (f32x4*)(out + (size_t)wave * AGG_D) + lane;
    __builtin_nontemporal_store(accv, dst);
}

extern "C" void kernel_launch(void* const* d_in, const int* in_sizes, int n_in,
                              void* d_out, int out_size, void* d_ws, size_t ws_size,
                              hipStream_t stream)
{
    const float* feat = (const float*)d_in[0];
    const int*   nbrs = (const int*)d_in[1];
    float*       out  = (float*)d_out;

    const int B = in_sizes[1] / AGG_S;           // 32768
    const int threads = 256;                     // 4 waves/block
    const int rows_per_block = threads / 64;
    const int blocks = (B + rows_per_block - 1) / rows_per_block;

    // PASS 1: cold (post-poison) gather.
    MeanAggregator_58514634441194_kernel<<<blocks, threads, 0, stream>>>(
        feat, nbrs, out, B);
    // PASS 2: identical, idempotent. Runs with whatever pass 1 left in
    // LLC/L2. dur delta vs r5 isolates the gather's standalone cost; the
    // warm/cold split discriminates the DRAM-bound vs LLC-reuse models.
    MeanAggregator_58514634441194_kernel<<<blocks, threads, 0, stream>>>(
        feat, nbrs, out, B);
}